// Round 8
// baseline (11944.645 us; speedup 1.0000x reference)
//
#include <hip/hip_runtime.h>
#include <stdint.h>

// Problem constants
#define Bb   4
#define Tt   32
#define Cc   132
#define Nn   512
#define HID  256
#define KNB  16
#define OUTC 260           // 4 + HID
#define G4   1024          // 4*HID gate rows
#define KP   160           // padded K for P-gemm (132 -> 160, 5 chunks of 32)
#define LDT  132           // LDS tile row stride (128 + 4 pad)

// Workspace layout (element counts)
#define WP_SZ (1024*KP)          // 163840 f
#define GI_SZ (Bb*Tt*Nn*KNB)     // 1048576 i
#define HT_SZ (Bb*HID*Nn)        // 524288 f
#define CB_SZ (Bb*Nn*HID)        // 524288 f
#define PQ_SZ (Bb*Nn*G4)         // 2097152 f

// Output offsets (floats): layer_output, h_f, c_f, group_ind
#define OFF_HF 17039360
#define OFF_CF 17563648
#define OFF_GI 18087936

// ---------------------------------------------------------------------------
// init: build W_P = w[:, :132] with first-4 columns reduced by w[:,132:136],
// zero-padded to K=160; zero h (transposed layout) and c buffer 0.
__global__ __launch_bounds__(256) void init_kernel(const float* __restrict__ w,
                                                   float* __restrict__ WP,
                                                   float* __restrict__ hT,
                                                   float* __restrict__ c0) {
  int i = blockIdx.x * 256 + threadIdx.x;
  if (i < WP_SZ) {
    int o = i / KP, c = i % KP;
    float v = 0.f;
    if (c < Cc) {
      v = w[(size_t)o * 392 + c];
      if (c < 4) v -= w[(size_t)o * 392 + 132 + c];
    }
    WP[i] = v;
  } else if (i < WP_SZ + HT_SZ) {
    hT[i - WP_SZ] = 0.f;
  } else if (i < WP_SZ + HT_SZ + CB_SZ) {
    c0[i - WP_SZ - HT_SZ] = 0.f;
  }
}

// ---------------------------------------------------------------------------
// KNN (R1 version, measured 170us, 0 bank conflicts): per (b,t), one thread
// per query, full 512-candidate scan, packed u64 compare-swap top-16.
// Exact fp32 replication of the XLA arithmetic; ties -> lower index.
__global__ __launch_bounds__(256) void knn_kernel(const float* __restrict__ x,
                                                  int* __restrict__ gi,
                                                  float* __restrict__ gi_f) {
  int bt = blockIdx.x >> 1;
  int b = bt >> 5, t = bt & 31;
  int tr = t > 0 ? t - 1 : 0;
  __shared__ float r0[Nn], r1[Nn], r2[Nn], rr[Nn];
  const float* xr = x + (size_t)(b * Tt + tr) * Cc * Nn;
  for (int m = threadIdx.x; m < Nn; m += 256) {
    float a0 = xr[m], a1 = xr[Nn + m], a2 = xr[2 * Nn + m];
    r0[m] = a0; r1[m] = a1; r2[m] = a2;
    rr[m] = __fadd_rn(__fadd_rn(__fmul_rn(a0, a0), __fmul_rn(a1, a1)), __fmul_rn(a2, a2));
  }
  __syncthreads();
  int n = ((blockIdx.x & 1) << 8) + threadIdx.x;
  const float* xq = x + (size_t)(b * Tt + t) * Cc * Nn;
  float q0 = xq[n], q1 = xq[Nn + n], q2 = xq[2 * Nn + n];
  float qq = __fadd_rn(__fadd_rn(__fmul_rn(q0, q0), __fmul_rn(q1, q1)), __fmul_rn(q2, q2));
  unsigned long long best[KNB];
#pragma unroll
  for (int s = 0; s < KNB; ++s) best[s] = 0xFFFFFFFFFFFFFFFFull;
  for (int m = 0; m < Nn; ++m) {
    float in = __fmaf_rn(q2, r2[m], __fmaf_rn(q1, r1[m], __fmul_rn(q0, r0[m])));
    float d2 = __fsub_rn(__fadd_rn(qq, rr[m]), __fmul_rn(2.0f, in));
    unsigned int bits = __float_as_uint(d2);
    unsigned int key = (bits & 0x80000000u) ? ~bits : (bits | 0x80000000u);
    unsigned long long cand = ((unsigned long long)key << 32) | (unsigned int)m;
#pragma unroll
    for (int s = 0; s < KNB; ++s) {
      bool sw = cand < best[s];
      unsigned long long lo = sw ? cand : best[s];
      cand = sw ? best[s] : cand;
      best[s] = lo;
    }
  }
  size_t ob = ((size_t)(b * Tt + t) * Nn + n) * KNB;
#pragma unroll
  for (int s = 0; s < KNB; ++s) {
    int idx = (int)(best[s] & 0xFFFFFFFFull);
    gi[ob + s] = idx;
    gi_f[ob + s] = (float)idx;
  }
}

// ---------------------------------------------------------------------------
// Fused P/Q GEMM. Blocks 0..127: P = W_P @ X_t + b. Blocks 128..255: Q.
// 128x128 tile, 512 threads (R7), micro 8(o)x4(n).
// SINGLE CHANGE vs R7: A (weights) no longer staged through LDS — per 4-kk
// group each thread loads its 8 A-row float4 fragments straight from global
// (16KB/chunk working set -> L1, 32-consecutive-float row reuse across kk).
// LDS holds only Bt: per-chunk LDS reads drop 786KB -> 262KB per CU.
// Same K-ascending per-output FMA chain + same zero guards -> bit-identical.
__global__ __launch_bounds__(512) void gemm_pq(const float* __restrict__ x,
                                               const float* __restrict__ w,
                                               const float* __restrict__ WP,
                                               const float* __restrict__ hT,
                                               const float* __restrict__ bias,
                                               float* __restrict__ Pb,
                                               float* __restrict__ Qb, int t) {
  const bool qm = blockIdx.x >= 128;
  const int bid = blockIdx.x & 127;
  const int b = bid >> 5;
  const int to = (bid >> 2) & 7;
  const int tn = bid & 3;
  const int o0 = to << 7, n0 = tn << 7;
  __shared__ float Bt[32 * LDT];
  const int tid = threadIdx.x;
  const int tx = tid & 31, ty = tid >> 5;   // tx: n-group 0..31, ty: o-group 0..15
  float acc[8][4];
#pragma unroll
  for (int i2 = 0; i2 < 8; ++i2) {
    float bv0 = 0.f;
    if (!qm) {
      int o = o0 + ((i2 < 4) ? (ty * 4 + i2) : (64 + ty * 4 + i2 - 4));
      bv0 = bias[o];
    }
#pragma unroll
    for (int j2 = 0; j2 < 4; ++j2) acc[i2][j2] = bv0;
  }
  const int tp = (t > 0) ? (t - 1) : 0;
  const int nch = qm ? 9 : 5;
  // A row base pointers (8 output rows per thread); Q cols offset by 132.
  const float* arow[8];
#pragma unroll
  for (int i2 = 0; i2 < 8; ++i2) {
    int o = o0 + ((i2 < 4) ? (ty * 4 + i2) : (64 + ty * 4 + i2 - 4));
    arow[i2] = qm ? (w + (size_t)o * 392 + 132) : (WP + (size_t)o * KP);
  }
  // B stage: 512 threads x 2 float4 (32c x 128j direct)
  const int bj4 = (tid & 31) * 4;  // j offset
  const int bcr = tid >> 5;        // c row 0..15; +p*16
  for (int ch = 0; ch < nch; ++ch) {
    const int kc = ch << 5;
    // stage B direct: Bt[cc][j]  (identical to R7)
#pragma unroll
    for (int p = 0; p < 2; ++p) {
      int cc = bcr + (p << 4);
      int c = kc + cc;
      float4 v = make_float4(0.f, 0.f, 0.f, 0.f);
      if (!qm) {
        if (c < Cc) v = *(const float4*)(x + ((size_t)(b * Tt + t) * Cc + c) * Nn + n0 + bj4);
      } else {
        if (c < 4)        v = *(const float4*)(x + ((size_t)(b * Tt + tp) * Cc + c) * Nn + n0 + bj4);
        else if (c < 260) v = *(const float4*)(hT + ((size_t)b * HID + (c - 4)) * Nn + n0 + bj4);
      }
      *(float4*)(Bt + cc * LDT + bj4) = v;
    }
    __syncthreads();
    // compute: 8 groups of 4 kk; per group load 8 A float4 from global (L1)
#pragma unroll
    for (int g = 0; g < 8; ++g) {
      const int gc = kc + (g << 2);
      float4 a4[8];
#pragma unroll
      for (int p = 0; p < 8; ++p) {
        float4 v = make_float4(0.f, 0.f, 0.f, 0.f);
        if (!qm || gc <= 256) v = *(const float4*)(arow[p] + gc);
        a4[p] = v;
      }
#pragma unroll
      for (int k2 = 0; k2 < 4; ++k2) {
        const int kk = (g << 2) + k2;
        const float* br = Bt + kk * LDT;
        float4 b0 = *(const float4*)(br + tx * 4);
        float av[8];
#pragma unroll
        for (int p = 0; p < 8; ++p) {
          float4 u = a4[p];
          av[p] = (k2 == 0) ? u.x : (k2 == 1) ? u.y : (k2 == 2) ? u.z : u.w;
        }
        float bw[4] = {b0.x, b0.y, b0.z, b0.w};
#pragma unroll
        for (int i2 = 0; i2 < 8; ++i2)
#pragma unroll
          for (int j2 = 0; j2 < 4; ++j2)
            acc[i2][j2] = __fmaf_rn(av[i2], bw[j2], acc[i2][j2]);
      }
    }
    __syncthreads();
  }
  float* outp = qm ? Qb : Pb;
#pragma unroll
  for (int j2 = 0; j2 < 4; ++j2) {
    int j = n0 + tx * 4 + j2;
    float* row = outp + ((size_t)b * Nn + j) * G4 + o0;
    *(float4*)(row + ty * 4)      = make_float4(acc[0][j2], acc[1][j2], acc[2][j2], acc[3][j2]);
    *(float4*)(row + 64 + ty * 4) = make_float4(acc[4][j2], acc[5][j2], acc[6][j2], acc[7][j2]);
  }
}

// ---------------------------------------------------------------------------
__device__ __forceinline__ float sigm(float v) { return 1.f / (1.f + __expf(-v)); }
__device__ __forceinline__ float tanh_f(float v) { return 1.f - 2.f / (__expf(2.f * v) + 1.f); }

// Pointwise LSTM + max-pool over 16 neighbors. XCD-aware decode (R6, +116us).
__global__ __launch_bounds__(256) void lstm_point(const float* __restrict__ Pb,
                                                  const float* __restrict__ Qb,
                                                  const float* __restrict__ cprev,
                                                  const int* __restrict__ gi,
                                                  float* __restrict__ ccur,
                                                  float* __restrict__ hT,
                                                  float* __restrict__ out, int t) {
  int i = blockIdx.x;
  int xcd = i & 7;
  int b = xcd >> 1;
  int n = ((i >> 3) << 1) | (xcd & 1);
  int hc = threadIdx.x;
  const float* pr = Pb + ((size_t)b * Nn + n) * G4;
  float pi = pr[hc], pf = pr[HID + hc], po = pr[2 * HID + hc], pg = pr[3 * HID + hc];
  const int* gr = gi + ((size_t)(b * Tt + t) * Nn + n) * KNB;
  float hmax = -3.4e38f, cmax = -3.4e38f;
#pragma unroll
  for (int k = 0; k < KNB; ++k) {
    int j = gr[k];
    const float* qr = Qb + ((size_t)b * Nn + j) * G4;
    float gi_ = pi + qr[hc];
    float gf_ = pf + qr[HID + hc];
    float go_ = po + qr[2 * HID + hc];
    float gg_ = pg + qr[3 * HID + hc];
    float cg = cprev[((size_t)b * Nn + j) * HID + hc];
    float iv = sigm(gi_), fv = sigm(gf_), ov = sigm(go_);
    float gv = tanh_f(gg_);
    float cn = __fmaf_rn(fv, cg, iv * gv);
    float hn = ov * tanh_f(cn);
    hmax = fmaxf(hmax, hn);
    cmax = fmaxf(cmax, cn);
  }
  ccur[((size_t)b * Nn + n) * HID + hc] = cmax;
  hT[((size_t)b * HID + hc) * Nn + n] = hmax;                      // for next-step Q-gemm
  out[((size_t)(b * Tt + t) * OUTC + 4 + hc) * Nn + n] = hmax;     // layer_output h part
}

// ---------------------------------------------------------------------------
// layer_output position channels (all t)
__global__ __launch_bounds__(256) void pos_copy(const float* __restrict__ x,
                                                float* __restrict__ out) {
  int i = blockIdx.x * 256 + threadIdx.x;  // B*T*4*N = 262144
  int n = i & 511;
  int c = (i >> 9) & 3;
  int bt = i >> 11;
  out[((size_t)bt * OUTC + c) * Nn + n] = x[((size_t)bt * Cc + c) * Nn + n];
}

// h_f (flat copy of hT) and c_f (transpose of final c buffer)
__global__ __launch_bounds__(256) void finalize(const float* __restrict__ hT,
                                                const float* __restrict__ cfin,
                                                float* __restrict__ out) {
  int i = blockIdx.x * 256 + threadIdx.x;  // < 524288
  out[OFF_HF + i] = hT[i];
  int n = i & 511;
  int rest = i >> 9;
  int hc = rest & 255;
  int b = rest >> 8;
  out[OFF_CF + i] = cfin[((size_t)b * Nn + n) * HID + hc];
}

// ---------------------------------------------------------------------------
extern "C" void kernel_launch(void* const* d_in, const int* in_sizes, int n_in,
                              void* d_out, int out_size, void* d_ws, size_t ws_size,
                              hipStream_t stream) {
  const float* x    = (const float*)d_in[0];
  const float* w    = (const float*)d_in[1];
  const float* bias = (const float*)d_in[2];
  float* out = (float*)d_out;

  float* WP = (float*)d_ws;
  int*   gi = (int*)(WP + WP_SZ);
  float* hT = (float*)(gi + GI_SZ);
  float* c0 = hT + HT_SZ;
  float* c1 = c0 + CB_SZ;
  float* Pb = c1 + CB_SZ;
  float* Qb = Pb + PQ_SZ;

  init_kernel<<<4736, 256, 0, stream>>>(w, WP, hT, c0);
  knn_kernel<<<256, 256, 0, stream>>>(x, gi, out + OFF_GI);
  pos_copy<<<1024, 256, 0, stream>>>(x, out);

  float* cp = c0;
  float* cn = c1;
  for (int t = 0; t < Tt; ++t) {
    gemm_pq<<<256, 512, 0, stream>>>(x, w, WP, hT, bias, Pb, Qb, t);
    lstm_point<<<2048, 256, 0, stream>>>(Pb, Qb, cp, gi, cn, hT, out, t);
    float* tmp = cp; cp = cn; cn = tmp;
  }
  finalize<<<2048, 256, 0, stream>>>(hT, cp, out);
}

// Round 9
// 2121.107 us; speedup vs baseline: 5.6313x; 5.6313x over previous
//
#include <hip/hip_runtime.h>
#include <stdint.h>

// Problem constants
#define Bb   4
#define Tt   32
#define Cc   132
#define Nn   512
#define HID  256
#define KNB  16
#define OUTC 260           // 4 + HID
#define G4   1024          // 4*HID gate rows
#define KP   160           // padded K for P-gemm (132 -> 160, 5 chunks of 32)
#define LDT  132           // A LDS row stride (128 + 4 pad)
#define LDTB 66            // B LDS row stride (64 + 2 pad)

// Workspace layout (element counts)
#define WP_SZ (1024*KP)          // 163840 f
#define GI_SZ (Bb*Tt*Nn*KNB)     // 1048576 i
#define HT_SZ (Bb*HID*Nn)        // 524288 f
#define CB_SZ (Bb*Nn*HID)        // 524288 f
#define PQ_SZ (Bb*Nn*G4)         // 2097152 f

// Output offsets (floats): layer_output, h_f, c_f, group_ind
#define OFF_HF 17039360
#define OFF_CF 17563648
#define OFF_GI 18087936

// ---------------------------------------------------------------------------
// init: build W_P = w[:, :132] with first-4 columns reduced by w[:,132:136],
// zero-padded to K=160; zero h (transposed layout) and c buffer 0.
__global__ __launch_bounds__(256) void init_kernel(const float* __restrict__ w,
                                                   float* __restrict__ WP,
                                                   float* __restrict__ hT,
                                                   float* __restrict__ c0) {
  int i = blockIdx.x * 256 + threadIdx.x;
  if (i < WP_SZ) {
    int o = i / KP, c = i % KP;
    float v = 0.f;
    if (c < Cc) {
      v = w[(size_t)o * 392 + c];
      if (c < 4) v -= w[(size_t)o * 392 + 132 + c];
    }
    WP[i] = v;
  } else if (i < WP_SZ + HT_SZ) {
    hT[i - WP_SZ] = 0.f;
  } else if (i < WP_SZ + HT_SZ + CB_SZ) {
    c0[i - WP_SZ - HT_SZ] = 0.f;
  }
}

// ---------------------------------------------------------------------------
// KNN (R1 version, measured 170us, 0 bank conflicts): per (b,t), one thread
// per query, full 512-candidate scan, packed u64 compare-swap top-16.
// Exact fp32 replication of the XLA arithmetic; ties -> lower index.
__global__ __launch_bounds__(256) void knn_kernel(const float* __restrict__ x,
                                                  int* __restrict__ gi,
                                                  float* __restrict__ gi_f) {
  int bt = blockIdx.x >> 1;
  int b = bt >> 5, t = bt & 31;
  int tr = t > 0 ? t - 1 : 0;
  __shared__ float r0[Nn], r1[Nn], r2[Nn], rr[Nn];
  const float* xr = x + (size_t)(b * Tt + tr) * Cc * Nn;
  for (int m = threadIdx.x; m < Nn; m += 256) {
    float a0 = xr[m], a1 = xr[Nn + m], a2 = xr[2 * Nn + m];
    r0[m] = a0; r1[m] = a1; r2[m] = a2;
    rr[m] = __fadd_rn(__fadd_rn(__fmul_rn(a0, a0), __fmul_rn(a1, a1)), __fmul_rn(a2, a2));
  }
  __syncthreads();
  int n = ((blockIdx.x & 1) << 8) + threadIdx.x;
  const float* xq = x + (size_t)(b * Tt + t) * Cc * Nn;
  float q0 = xq[n], q1 = xq[Nn + n], q2 = xq[2 * Nn + n];
  float qq = __fadd_rn(__fadd_rn(__fmul_rn(q0, q0), __fmul_rn(q1, q1)), __fmul_rn(q2, q2));
  unsigned long long best[KNB];
#pragma unroll
  for (int s = 0; s < KNB; ++s) best[s] = 0xFFFFFFFFFFFFFFFFull;
  for (int m = 0; m < Nn; ++m) {
    float in = __fmaf_rn(q2, r2[m], __fmaf_rn(q1, r1[m], __fmul_rn(q0, r0[m])));
    float d2 = __fsub_rn(__fadd_rn(qq, rr[m]), __fmul_rn(2.0f, in));
    unsigned int bits = __float_as_uint(d2);
    unsigned int key = (bits & 0x80000000u) ? ~bits : (bits | 0x80000000u);
    unsigned long long cand = ((unsigned long long)key << 32) | (unsigned int)m;
#pragma unroll
    for (int s = 0; s < KNB; ++s) {
      bool sw = cand < best[s];
      unsigned long long lo = sw ? cand : best[s];
      cand = sw ? best[s] : cand;
      best[s] = lo;
    }
  }
  size_t ob = ((size_t)(b * Tt + t) * Nn + n) * KNB;
#pragma unroll
  for (int s = 0; s < KNB; ++s) {
    int idx = (int)(best[s] & 0xFFFFFFFFull);
    gi[ob + s] = idx;
    gi_f[ob + s] = (float)idx;
  }
}

// ---------------------------------------------------------------------------
// Fused P/Q GEMM v5. Blocks 0..255: Q(t). Blocks 256..511: P(t) + bias.
// Tile 128(o) x 64(n), 512 threads, micro 8(o)x2(n) -> 512 blocks =
// 2 blocks/CU = 4 waves/SIMD (R7 had 2). A/B staged in LDS exactly like R7;
// A-fragment reads are wave-uniform broadcasts (2 ty values/wave, free);
// B-fragment is ds_read_b64, conflict-free. Per-output FMA chain (bias init,
// ascending K, zero-padded tails) identical to R1/R6/R7 -> bitwise identical.
__global__ __launch_bounds__(512, 4) void gemm_pq(const float* __restrict__ x,
                                                  const float* __restrict__ w,
                                                  const float* __restrict__ WP,
                                                  const float* __restrict__ hT,
                                                  const float* __restrict__ bias,
                                                  float* __restrict__ Pb,
                                                  float* __restrict__ Qb, int t) {
  const bool qm = blockIdx.x < 256;
  const int bid = blockIdx.x & 255;
  const int b = bid >> 6;
  const int to = (bid >> 3) & 7;
  const int tn = bid & 7;
  const int o0 = to << 7, n0 = tn << 6;
  __shared__ float At[32 * LDT];
  __shared__ float Bt[32 * LDTB];
  const int tid = threadIdx.x;
  const int tx = tid & 31, ty = tid >> 5;   // tx: n-pair 0..31, ty: o-group 0..15
  float acc[8][2];
#pragma unroll
  for (int i2 = 0; i2 < 8; ++i2) {
    float bv0 = 0.f;
    if (!qm) {
      int o = o0 + ((i2 < 4) ? (ty * 4 + i2) : (64 + ty * 4 + i2 - 4));
      bv0 = bias[o];
    }
#pragma unroll
    for (int j2 = 0; j2 < 2; ++j2) acc[i2][j2] = bv0;
  }
  const int tp = (t > 0) ? (t - 1) : 0;
  const int nch = qm ? 9 : 5;
  // A stage (same mapping as R7): 512 threads x 2 float4 = 32c x 128o transposed
  const int acb = (tid & 3) * 4;   // c offset {0,4,8,12}; +p*16
  const int aor = tid >> 2;        // o row 0..127
  // B stage: 32c x 64j direct = 512 float4, one per thread
  const int bj4 = (tid & 15) * 4;  // j offset
  const int bcr = tid >> 4;        // c row 0..31
  for (int ch = 0; ch < nch; ++ch) {
    const int kc = ch << 5;
    // stage A transposed: At[cc][o]
#pragma unroll
    for (int p = 0; p < 2; ++p) {
      int c = acb + (p << 4);
      int gc = kc + c;
      float4 v = make_float4(0.f, 0.f, 0.f, 0.f);
      if (!qm) {
        v = *(const float4*)(WP + (size_t)(o0 + aor) * KP + gc);
      } else {
        if (gc <= 256) v = *(const float4*)(w + (size_t)(o0 + aor) * 392 + 132 + gc);
      }
      At[(c + 0) * LDT + aor] = v.x;
      At[(c + 1) * LDT + aor] = v.y;
      At[(c + 2) * LDT + aor] = v.z;
      At[(c + 3) * LDT + aor] = v.w;
    }
    // stage B direct: Bt[cc][j]
    {
      int c = kc + bcr;
      float4 v = make_float4(0.f, 0.f, 0.f, 0.f);
      if (!qm) {
        if (c < Cc) v = *(const float4*)(x + ((size_t)(b * Tt + t) * Cc + c) * Nn + n0 + bj4);
      } else {
        if (c < 4)        v = *(const float4*)(x + ((size_t)(b * Tt + tp) * Cc + c) * Nn + n0 + bj4);
        else if (c < 260) v = *(const float4*)(hT + ((size_t)b * HID + (c - 4)) * Nn + n0 + bj4);
      }
      *(float4*)(Bt + bcr * LDTB + bj4) = v;
    }
    __syncthreads();
#pragma unroll
    for (int kk = 0; kk < 32; ++kk) {
      const float* ar = At + kk * LDT;
      const float* br = Bt + kk * LDTB;
      float4 a0 = *(const float4*)(ar + ty * 4);        // wave-broadcast
      float4 a1 = *(const float4*)(ar + 64 + ty * 4);   // wave-broadcast
      float2 b0 = *(const float2*)(br + tx * 2);
      float av[8] = {a0.x, a0.y, a0.z, a0.w, a1.x, a1.y, a1.z, a1.w};
      float bw[2] = {b0.x, b0.y};
#pragma unroll
      for (int i2 = 0; i2 < 8; ++i2)
#pragma unroll
        for (int j2 = 0; j2 < 2; ++j2)
          acc[i2][j2] = __fmaf_rn(av[i2], bw[j2], acc[i2][j2]);
    }
    __syncthreads();
  }
  float* outp = qm ? Qb : Pb;
#pragma unroll
  for (int j2 = 0; j2 < 2; ++j2) {
    int j = n0 + tx * 2 + j2;
    float* row = outp + ((size_t)b * Nn + j) * G4 + o0;
    *(float4*)(row + ty * 4)      = make_float4(acc[0][j2], acc[1][j2], acc[2][j2], acc[3][j2]);
    *(float4*)(row + 64 + ty * 4) = make_float4(acc[4][j2], acc[5][j2], acc[6][j2], acc[7][j2]);
  }
}

// ---------------------------------------------------------------------------
__device__ __forceinline__ float sigm(float v) { return 1.f / (1.f + __expf(-v)); }
__device__ __forceinline__ float tanh_f(float v) { return 1.f - 2.f / (__expf(2.f * v) + 1.f); }

// Pointwise LSTM + max-pool over 16 neighbors. XCD-aware decode (R6, +116us).
__global__ __launch_bounds__(256) void lstm_point(const float* __restrict__ Pb,
                                                  const float* __restrict__ Qb,
                                                  const float* __restrict__ cprev,
                                                  const int* __restrict__ gi,
                                                  float* __restrict__ ccur,
                                                  float* __restrict__ hT,
                                                  float* __restrict__ out, int t) {
  int i = blockIdx.x;
  int xcd = i & 7;
  int b = xcd >> 1;
  int n = ((i >> 3) << 1) | (xcd & 1);
  int hc = threadIdx.x;
  const float* pr = Pb + ((size_t)b * Nn + n) * G4;
  float pi = pr[hc], pf = pr[HID + hc], po = pr[2 * HID + hc], pg = pr[3 * HID + hc];
  const int* gr = gi + ((size_t)(b * Tt + t) * Nn + n) * KNB;
  float hmax = -3.4e38f, cmax = -3.4e38f;
#pragma unroll
  for (int k = 0; k < KNB; ++k) {
    int j = gr[k];
    const float* qr = Qb + ((size_t)b * Nn + j) * G4;
    float gi_ = pi + qr[hc];
    float gf_ = pf + qr[HID + hc];
    float go_ = po + qr[2 * HID + hc];
    float gg_ = pg + qr[3 * HID + hc];
    float cg = cprev[((size_t)b * Nn + j) * HID + hc];
    float iv = sigm(gi_), fv = sigm(gf_), ov = sigm(go_);
    float gv = tanh_f(gg_);
    float cn = __fmaf_rn(fv, cg, iv * gv);
    float hn = ov * tanh_f(cn);
    hmax = fmaxf(hmax, hn);
    cmax = fmaxf(cmax, cn);
  }
  ccur[((size_t)b * Nn + n) * HID + hc] = cmax;
  hT[((size_t)b * HID + hc) * Nn + n] = hmax;                      // for next-step Q-gemm
  out[((size_t)(b * Tt + t) * OUTC + 4 + hc) * Nn + n] = hmax;     // layer_output h part
}

// ---------------------------------------------------------------------------
// layer_output position channels (all t)
__global__ __launch_bounds__(256) void pos_copy(const float* __restrict__ x,
                                                float* __restrict__ out) {
  int i = blockIdx.x * 256 + threadIdx.x;  // B*T*4*N = 262144
  int n = i & 511;
  int c = (i >> 9) & 3;
  int bt = i >> 11;
  out[((size_t)bt * OUTC + c) * Nn + n] = x[((size_t)bt * Cc + c) * Nn + n];
}

// h_f (flat copy of hT) and c_f (transpose of final c buffer)
__global__ __launch_bounds__(256) void finalize(const float* __restrict__ hT,
                                                const float* __restrict__ cfin,
                                                float* __restrict__ out) {
  int i = blockIdx.x * 256 + threadIdx.x;  // < 524288
  out[OFF_HF + i] = hT[i];
  int n = i & 511;
  int rest = i >> 9;
  int hc = rest & 255;
  int b = rest >> 8;
  out[OFF_CF + i] = cfin[((size_t)b * Nn + n) * HID + hc];
}

// ---------------------------------------------------------------------------
extern "C" void kernel_launch(void* const* d_in, const int* in_sizes, int n_in,
                              void* d_out, int out_size, void* d_ws, size_t ws_size,
                              hipStream_t stream) {
  const float* x    = (const float*)d_in[0];
  const float* w    = (const float*)d_in[1];
  const float* bias = (const float*)d_in[2];
  float* out = (float*)d_out;

  float* WP = (float*)d_ws;
  int*   gi = (int*)(WP + WP_SZ);
  float* hT = (float*)(gi + GI_SZ);
  float* c0 = hT + HT_SZ;
  float* c1 = c0 + CB_SZ;
  float* Pb = c1 + CB_SZ;
  float* Qb = Pb + PQ_SZ;

  init_kernel<<<4736, 256, 0, stream>>>(w, WP, hT, c0);
  knn_kernel<<<256, 256, 0, stream>>>(x, gi, out + OFF_GI);
  pos_copy<<<1024, 256, 0, stream>>>(x, out);

  float* cp = c0;
  float* cn = c1;
  for (int t = 0; t < Tt; ++t) {
    gemm_pq<<<512, 512, 0, stream>>>(x, w, WP, hT, bias, Pb, Qb, t);
    lstm_point<<<2048, 256, 0, stream>>>(Pb, Qb, cp, gi, cn, hT, out, t);
    float* tmp = cp; cp = cn; cn = tmp;
  }
  finalize<<<2048, 256, 0, stream>>>(hT, cp, out);
}